// Round 8
// baseline (141.074 us; speedup 1.0000x reference)
//
#include <hip/hip_runtime.h>

// Problem constants (from reference)
constexpr int Bn    = 262144;
constexpr int NNUM  = 64;
constexpr int FCAT  = 32;
constexpr int NCAT  = 8;
constexpr int NFEAT = NNUM + FCAT * NCAT;  // 320
constexpr int NPHEN = NNUM + FCAT;         // 96

typedef float fx4 __attribute__((ext_vector_type(4)));

// tanh(x) given a = 2x:  tanh(x) = 1 - 2/(exp(2x)+1)
__device__ __forceinline__ float tanh_from_2x(float a) {
    float e = __expf(a);
    float r = __builtin_amdgcn_rcpf(e + 1.0f);
    return fmaf(-2.0f, r, 1.0f);
}

__global__ __launch_bounds__(256, 4) void model_kernel(
    const float* __restrict__ num_x,   // (B, 64)
    const float* __restrict__ cat_x,   // (32, B, 8)
    const float* __restrict__ W,       // (2, 320)
    const float* __restrict__ M,       // (2, 96)
    float* __restrict__ out)           // (2, B)
{
    __shared__ float sW2[2 * NFEAT];   // 2*W: dot feeds exp(2x) directly
    __shared__ float sM[2 * NPHEN];
    const int tid = threadIdx.x;
    for (int i = tid; i < 2 * NFEAT; i += 256) sW2[i] = 2.0f * W[i];
    for (int i = tid; i < 2 * NPHEN; i += 256) sM[i] = M[i];

    const int b = blockIdx.x * 256 + tid;
    const float* cbase = cat_x + (size_t)b * NCAT;
    const size_t fstride = (size_t)Bn * NCAT;   // per-f stride (floats)

    // ---- (a) issue ALL 16 num loads up front (8 KB/wave in flight) ----
    const fx4* nx = reinterpret_cast<const fx4*>(num_x + (size_t)b * NNUM);
    fx4 nv[16];
    #pragma unroll
    for (int i = 0; i < 16; ++i) nv[i] = nx[i];

    // ---- (b) issue cat group 0 (4 f's x 2 fx4) before num compute ----
    fx4 bufA[8], bufB[8];
    #pragma unroll
    for (int q = 0; q < 4; ++q) {
        const fx4* cx = reinterpret_cast<const fx4*>(cbase + (size_t)q * fstride);
        bufA[q * 2 + 0] = cx[0];
        bufA[q * 2 + 1] = cx[1];
    }

    __syncthreads();

    float f0 = 0.0f, f1 = 0.0f;

    // ---- numerical compute (loads already in flight / landed) ----
    #pragma unroll
    for (int i = 0; i < 16; ++i) {
        #pragma unroll
        for (int j = 0; j < 4; ++j) {
            const int k = i * 4 + j;
            float x = nv[i][j];
            f0 = fmaf(sM[k],         tanh_from_2x(sW2[k] * x),         f0);
            f1 = fmaf(sM[NPHEN + k], tanh_from_2x(sW2[NFEAT + k] * x), f1);
        }
    }

    // ---- (c) cat: register double-buffer, prefetch g+1 during compute g ----
    #pragma unroll
    for (int g = 0; g < 8; ++g) {
        fx4* cur = (g & 1) ? bufB : bufA;   // static after full unroll
        fx4* nxt = (g & 1) ? bufA : bufB;
        if (g < 7) {
            #pragma unroll
            for (int q = 0; q < 4; ++q) {
                const int f = (g + 1) * 4 + q;
                const fx4* cx = reinterpret_cast<const fx4*>(cbase + (size_t)f * fstride);
                nxt[q * 2 + 0] = cx[0];
                nxt[q * 2 + 1] = cx[1];
            }
        }
        #pragma unroll
        for (int q = 0; q < 4; ++q) {
            const int f = g * 4 + q;
            const fx4 v0 = cur[q * 2 + 0];
            const fx4 v1 = cur[q * 2 + 1];
            const float* w0 = &sW2[NNUM + f * NCAT];           // 2*W_cat[0][f][:]
            const float* w1 = &sW2[NFEAT + NNUM + f * NCAT];   // 2*W_cat[1][f][:]
            float d0 = 0.0f, d1 = 0.0f;                        // 2*dot
            #pragma unroll
            for (int n = 0; n < 4; ++n) {
                d0 = fmaf(w0[n], v0[n], d0);
                d1 = fmaf(w1[n], v0[n], d1);
            }
            #pragma unroll
            for (int n = 0; n < 4; ++n) {
                d0 = fmaf(w0[4 + n], v1[n], d0);
                d1 = fmaf(w1[4 + n], v1[n], d1);
            }
            f0 = fmaf(sM[NNUM + f],         tanh_from_2x(d0), f0);
            f1 = fmaf(sM[NPHEN + NNUM + f], tanh_from_2x(d1), f1);
        }
    }

    // ---- stable 2-class softmax ----
    float e10 = __expf(f1 - f0);
    float o0  = __builtin_amdgcn_rcpf(1.0f + e10);
    out[b]              = o0;
    out[(size_t)Bn + b] = 1.0f - o0;
}

extern "C" void kernel_launch(void* const* d_in, const int* in_sizes, int n_in,
                              void* d_out, int out_size, void* d_ws, size_t ws_size,
                              hipStream_t stream) {
    const float* num_x = (const float*)d_in[0];
    const float* cat_x = (const float*)d_in[1];
    const float* W     = (const float*)d_in[2];
    const float* M     = (const float*)d_in[3];
    float* out = (float*)d_out;

    dim3 grid(Bn / 256), block(256);
    hipLaunchKernelGGL(model_kernel, grid, block, 0, stream,
                       num_x, cat_x, W, M, out);
}

// Round 9
// 80.439 us; speedup vs baseline: 1.7538x; 1.7538x over previous
//
#include <hip/hip_runtime.h>

// Problem constants (from reference)
constexpr int Bn    = 262144;
constexpr int NNUM  = 64;
constexpr int FCAT  = 32;
constexpr int NCAT  = 8;
constexpr int NFEAT = NNUM + FCAT * NCAT;  // 320
constexpr int NPHEN = NNUM + FCAT;         // 96

typedef float fx4 __attribute__((ext_vector_type(4)));

// tanh(x) given a = 2x:  tanh(x) = 1 - 2/(exp(2x)+1)
__device__ __forceinline__ float tanh_from_2x(float a) {
    float e = __expf(a);
    float r = __builtin_amdgcn_rcpf(e + 1.0f);
    return fmaf(-2.0f, r, 1.0f);
}

// Homogeneous interleave: 8 groups, each = {2 num fx4 + 4 cat f loads} +
// {8 num feats + 4 cat dots compute}. Keeps HBM demand flat through the
// kernel instead of a compute-gated num phase followed by a load-heavy
// cat phase. Small register footprint (~10 live fx4) to avoid R8's
// allocator serialization.
__global__ __launch_bounds__(256) void model_kernel(
    const float* __restrict__ num_x,   // (B, 64)
    const float* __restrict__ cat_x,   // (32, B, 8)
    const float* __restrict__ W,       // (2, 320)
    const float* __restrict__ M,       // (2, 96)
    float* __restrict__ out)           // (2, B)
{
    __shared__ float sW2[2 * NFEAT];   // 2*W: dot feeds exp(2x) directly
    __shared__ float sM[2 * NPHEN];
    const int tid = threadIdx.x;
    for (int i = tid; i < 2 * NFEAT; i += 256) sW2[i] = 2.0f * W[i];
    for (int i = tid; i < 2 * NPHEN; i += 256) sM[i] = M[i];
    __syncthreads();

    const int b = blockIdx.x * 256 + tid;
    const fx4* nx = reinterpret_cast<const fx4*>(num_x + (size_t)b * NNUM);
    const float* cbase = cat_x + (size_t)b * NCAT;
    const size_t fstride = (size_t)Bn * NCAT;   // per-f stride (floats)

    float f0 = 0.0f, f1 = 0.0f;

    #pragma unroll
    for (int g = 0; g < 8; ++g) {
        // ---- group loads: 2 num fx4 + 4 cat f's (8 fx4) ----
        fx4 n0 = nx[2 * g];
        fx4 n1 = nx[2 * g + 1];
        fx4 c[8];
        #pragma unroll
        for (int q = 0; q < 4; ++q) {
            const fx4* cx = reinterpret_cast<const fx4*>(
                cbase + (size_t)(g * 4 + q) * fstride);
            c[2 * q]     = cx[0];
            c[2 * q + 1] = cx[1];
        }

        // ---- num compute: feats 8g .. 8g+7 ----
        #pragma unroll
        for (int j = 0; j < 4; ++j) {
            const int k = g * 8 + j;
            f0 = fmaf(sM[k],         tanh_from_2x(sW2[k] * n0[j]),         f0);
            f1 = fmaf(sM[NPHEN + k], tanh_from_2x(sW2[NFEAT + k] * n0[j]), f1);
        }
        #pragma unroll
        for (int j = 0; j < 4; ++j) {
            const int k = g * 8 + 4 + j;
            f0 = fmaf(sM[k],         tanh_from_2x(sW2[k] * n1[j]),         f0);
            f1 = fmaf(sM[NPHEN + k], tanh_from_2x(sW2[NFEAT + k] * n1[j]), f1);
        }

        // ---- cat compute: f = 4g .. 4g+3 ----
        #pragma unroll
        for (int q = 0; q < 4; ++q) {
            const int f = g * 4 + q;
            const fx4 v0 = c[2 * q];
            const fx4 v1 = c[2 * q + 1];
            const float* w0 = &sW2[NNUM + f * NCAT];           // 2*W_cat[0][f][:]
            const float* w1 = &sW2[NFEAT + NNUM + f * NCAT];   // 2*W_cat[1][f][:]
            float d0 = 0.0f, d1 = 0.0f;                        // 2*dot
            #pragma unroll
            for (int n = 0; n < 4; ++n) {
                d0 = fmaf(w0[n], v0[n], d0);
                d1 = fmaf(w1[n], v0[n], d1);
            }
            #pragma unroll
            for (int n = 0; n < 4; ++n) {
                d0 = fmaf(w0[4 + n], v1[n], d0);
                d1 = fmaf(w1[4 + n], v1[n], d1);
            }
            f0 = fmaf(sM[NNUM + f],         tanh_from_2x(d0), f0);
            f1 = fmaf(sM[NPHEN + NNUM + f], tanh_from_2x(d1), f1);
        }
    }

    // ---- stable 2-class softmax ----
    float e10 = __expf(f1 - f0);
    float o0  = __builtin_amdgcn_rcpf(1.0f + e10);
    out[b]              = o0;
    out[(size_t)Bn + b] = 1.0f - o0;
}

extern "C" void kernel_launch(void* const* d_in, const int* in_sizes, int n_in,
                              void* d_out, int out_size, void* d_ws, size_t ws_size,
                              hipStream_t stream) {
    const float* num_x = (const float*)d_in[0];
    const float* cat_x = (const float*)d_in[1];
    const float* W     = (const float*)d_in[2];
    const float* M     = (const float*)d_in[3];
    float* out = (float*)d_out;

    dim3 grid(Bn / 256), block(256);
    hipLaunchKernelGGL(model_kernel, grid, block, 0, stream,
                       num_x, cat_x, W, M, out);
}